// Round 5
// baseline (143.099 us; speedup 1.0000x reference)
//
#include <hip/hip_runtime.h>

// OccupancyGridForestAS: per-point voxel lookup in a forest of 64 dense 64^3 grids,
// addressed via an 8^3 block->tree lookup table.
//
// Inputs (setup_inputs order):
//   d_in[0]: pts            float32 [4194304, 3]   (48 MiB, streamed)
//   d_in[1]: occ_val_grid   float32 [64, 64, 64, 64] (64 MiB, random 4B gathers)
//   d_in[2]: block_lookup   int32   [8, 8, 8]      (2 KiB)
// Output: float32 [4194304] (16 MiB, streamed)
//
// R7 -> R8 (post-mortem): R7 pipelining = best yet (~42 us/launch) but 4
// structures now cluster at 42-47 us with HBM ~32% and VALU ~12% -- both pipes
// idle. Revised model: READ-CONCURRENCY ceiling. The harness fill kernel does
// 268 MB write-only at 6.5 TB/s, but R6's pure sequential read sweep ran at
// ~2.8 TB/s: writes are fire-and-forget, reads hold an MSHR for full HBM
// latency (~900cy cold). ~64 line-misses/CU in flight -> 64*64B/375ns*256CU
// ~= 2.8 TB/s read ceiling, where every variant lands.
//
// R8 is a DECISIVE SPLIT PROBE: two stream-ordered kernels, separate rocprof
// rows per access class (the diagnostic we've been missing):
//  * K1 (copy-class): read pts 48 MB -> idx (invalid = -1) -> write idx into
//    the OUT buffer reinterpreted as int (16 MB; no workspace needed). Pure
//    stream, zero dependent load phases. Its measured TB/s = the chip's true
//    read-stream rate under harness conditions.
//  * K2 (gather-class): read idx 16 MB (L2-warm: identical grid & block->XCD
//    mapping as K1's writes), 4 independent gathers each, overwrite with vals.
//  * NO nontemporal anywhere this round (R4 entangled nt with prefetch
//    removal; kill the variable). Plain cached loads/stores.

#define LDIM 8
#define RES  64

typedef float v4f __attribute__((ext_vector_type(4)));
typedef int   v4i __attribute__((ext_vector_type(4)));

// --- K1: pts -> gather-index stream. 4 points per thread. ---
__global__ __launch_bounds__(256) void idx_kernel(
    const v4f* __restrict__ pts4,
    const int* __restrict__ lookup,
    v4i*       __restrict__ oidx,   // out buffer reinterpreted as int4
    int T)                          // total threads = N/4
{
    __shared__ int slut[LDIM * LDIM * LDIM];  // 512 ints = 2 KB
    ((int2*)slut)[threadIdx.x] = ((const int2*)lookup)[threadIdx.x];
    __syncthreads();  // before any global load: vmcnt drain is free

    int j = blockIdx.x * blockDim.x + threadIdx.x;

    // 4 points = 12 floats = 3 float4, fully coalesced cached loads.
    const v4f* p = pts4 + 3 * j;
    v4f q0 = p[0];
    v4f q1 = p[1];
    v4f q2 = p[2];

    const float xs[4] = {q0.x, q0.w, q1.z, q2.y};
    const float ys[4] = {q0.y, q1.x, q1.w, q2.z};
    const float zs[4] = {q0.z, q1.y, q2.x, q2.w};

    int idx[4];
#pragma unroll
    for (int k = 0; k < 4; ++k) {
        float x = xs[k], y = ys[k], z = zs[k];

        int bx = (int)floorf(x);
        int by = (int)floorf(y);
        int bz = (int)floorf(z);
        bool in_dom = (bx >= 0) & (bx < LDIM) &
                      (by >= 0) & (by < LDIM) &
                      (bz >= 0) & (bz < LDIM);
        int cx = min(max(bx, 0), LDIM - 1);
        int cy = min(max(by, 0), LDIM - 1);
        int cz = min(max(bz, 0), LDIM - 1);

        int bidx = slut[(cx * LDIM + cy) * LDIM + cz];
        bool v = in_dom & (bidx >= 0);

        // Reference float op sequence, replicated exactly:
        // block_x = 2*(p - bcs) - 1 ; t = (block_x*0.5 + 0.5)*res ; vox = clip(floor(t),0,res-1)
        float bxf = 2.0f * (x - (float)cx) - 1.0f;
        float byf = 2.0f * (y - (float)cy) - 1.0f;
        float bzf = 2.0f * (z - (float)cz) - 1.0f;
        float tx = (bxf * 0.5f + 0.5f) * (float)RES;
        float ty = (byf * 0.5f + 0.5f) * (float)RES;
        float tz = (bzf * 0.5f + 0.5f) * (float)RES;
        int vx = min(max((int)floorf(tx), 0), RES - 1);
        int vy = min(max((int)floorf(ty), 0), RES - 1);
        int vz = min(max((int)floorf(tz), 0), RES - 1);

        int ii = ((bidx * RES + vx) * RES + vy) * RES + vz;  // < 2^24 when valid
        idx[k] = v ? ii : -1;   // invalid encoded as negative
    }

    v4i o = {idx[0], idx[1], idx[2], idx[3]};
    oidx[j] = o;
}

// --- K2: idx -> gathered values. Same grid shape/mapping as K1 (L2 reuse). ---
__global__ __launch_bounds__(256) void gather_kernel(
    const float* __restrict__ grid,
    v4i*         __restrict__ io,   // out buffer: read idx, write float bits
    int T)
{
    int j = blockIdx.x * blockDim.x + threadIdx.x;

    v4i idx = io[j];   // coalesced 16B, mostly L2-hit (written by same XCD in K1)

    // 4 independent gathers, all in flight at once. Invalid (negative) ->
    // grid[0]: same-line broadcast across the wave, ~free.
    float vals[4];
#pragma unroll
    for (int k = 0; k < 4; ++k) {
        int i = idx[k];
        vals[k] = grid[i < 0 ? 0 : i];
    }

    v4i o;
#pragma unroll
    for (int k = 0; k < 4; ++k) {
        o[k] = __float_as_int(idx[k] < 0 ? 0.0f : vals[k]);
    }
    io[j] = o;
}

extern "C" void kernel_launch(void* const* d_in, const int* in_sizes, int n_in,
                              void* d_out, int out_size, void* d_ws, size_t ws_size,
                              hipStream_t stream) {
    const float* pts    = (const float*)d_in[0];
    const float* grid   = (const float*)d_in[1];
    const int*   lookup = (const int*)d_in[2];

    // out_size = 4194304 points; 4 points per thread in both kernels.
    int T = out_size / 4;                       // 1048576 threads
    int threads = 256;
    int blocks = (T + threads - 1) / threads;   // 4096 blocks (same for K1, K2)

    idx_kernel<<<blocks, threads, 0, stream>>>(
        (const v4f*)pts, lookup, (v4i*)d_out, T);
    gather_kernel<<<blocks, threads, 0, stream>>>(
        grid, (v4i*)d_out, T);
}

// Round 6
// 138.562 us; speedup vs baseline: 1.0327x; 1.0327x over previous
//
#include <hip/hip_runtime.h>

// OccupancyGridForestAS: per-point voxel lookup in a forest of 64 dense 64^3 grids,
// addressed via an 8^3 block->tree lookup table.
//
// Inputs (setup_inputs order):
//   d_in[0]: pts            float32 [4194304, 3]   (48 MiB, streamed)
//   d_in[1]: occ_val_grid   float32 [64, 64, 64, 64] (64 MiB, random 4B gathers)
//   d_in[2]: block_lookup   int32   [8, 8, 8]      (2 KiB)
// Output: float32 [4194304] (16 MiB, streamed)
//
// R8 -> R9 (post-mortem): the split probe regressed (+3 us/launch: 32 MB idx
// round-trip + extra launch) and the per-class dispatch rows stayed hidden
// below the 40 us fill rows. Correction to R5's post-mortem: R0's "warm
// replay still 42 us" row had FETCH=NaN (not collected), NOT zero -- that
// anomaly is retracted. Surviving facts: all structures 42-47 us/launch at
// ~2.5 TB/s; the only two real wins were issue-continuity levers (ordered
// prefetch +3, 2-deep pipeline +3).
//
// R9: push memory-level parallelism to the limit. 16 points/thread; ALL 12
// pts loads + ALL 16 gathers issue before the FIRST dependent wait:
//   pts(c0,c1) | pts(c2)+gather(c0) | pts(c3)+gather(c1) | gather(c2) |
//   gather(c3) | store c0..c3 with descending vmcnt(12/8/4/0).
// First store's gathers get ~3 iterations of ALU+issue to land; peak 28 vmem
// ops in flight per thread (R7: 10). 2048 blocks x 128 threads = 16 waves/CU
// (TLP halved, per-wave ILP ~3x). No nt, no sweep, no split -- isolate depth.

#define LDIM 8
#define RES  64

typedef float v4f __attribute__((ext_vector_type(4)));
typedef int   v4i __attribute__((ext_vector_type(4)));

// Compute gather indices for 4 points packed in 3 float4s.
__device__ __forceinline__ void compute_idx4(
    const int* __restrict__ slut, v4f q0, v4f q1, v4f q2,
    int idx[4], bool valid[4])
{
    const float xs[4] = {q0.x, q0.w, q1.z, q2.y};
    const float ys[4] = {q0.y, q1.x, q1.w, q2.z};
    const float zs[4] = {q0.z, q1.y, q2.x, q2.w};
#pragma unroll
    for (int k = 0; k < 4; ++k) {
        float x = xs[k], y = ys[k], z = zs[k];

        int bx = (int)floorf(x);
        int by = (int)floorf(y);
        int bz = (int)floorf(z);
        bool in_dom = (bx >= 0) & (bx < LDIM) &
                      (by >= 0) & (by < LDIM) &
                      (bz >= 0) & (bz < LDIM);
        int cx = min(max(bx, 0), LDIM - 1);
        int cy = min(max(by, 0), LDIM - 1);
        int cz = min(max(bz, 0), LDIM - 1);

        int bidx = slut[(cx * LDIM + cy) * LDIM + cz];
        bool v = in_dom & (bidx >= 0);

        // Reference float op sequence, replicated exactly:
        // block_x = 2*(p - bcs) - 1 ; t = (block_x*0.5 + 0.5)*res ; vox = clip(floor(t),0,res-1)
        float bxf = 2.0f * (x - (float)cx) - 1.0f;
        float byf = 2.0f * (y - (float)cy) - 1.0f;
        float bzf = 2.0f * (z - (float)cz) - 1.0f;
        float tx = (bxf * 0.5f + 0.5f) * (float)RES;
        float ty = (byf * 0.5f + 0.5f) * (float)RES;
        float tz = (bzf * 0.5f + 0.5f) * (float)RES;
        int vx = min(max((int)floorf(tx), 0), RES - 1);
        int vy = min(max((int)floorf(ty), 0), RES - 1);
        int vz = min(max((int)floorf(tz), 0), RES - 1);

        int sb = v ? bidx : 0;
        int ii = ((sb * RES + vx) * RES + vy) * RES + vz;  // < 2^24
        idx[k]   = v ? ii : 0;   // invalid -> grid[0]: same-line broadcast
        valid[k] = v;
    }
}

__global__ __launch_bounds__(128, 4) void occ_forest_kernel(
    const v4f*    __restrict__ pts4,
    const float*  __restrict__ grid,
    const int*    __restrict__ lookup,
    v4f*          __restrict__ out4,
    int T)        // total threads; thread j handles 4-pt chunks j, j+T, j+2T, j+3T
{
    __shared__ int slut[LDIM * LDIM * LDIM];  // 512 ints = 2 KB

    // Stage lookup table: 128 threads x int4 (16B) = 2 KB, coalesced.
    ((v4i*)slut)[threadIdx.x] = ((const v4i*)lookup)[threadIdx.x];
    // Barrier BEFORE any global load: its vmcnt(0) drain costs nothing.
    __syncthreads();

    int j = blockIdx.x * blockDim.x + threadIdx.x;

    // --- Issue pts loads, chunks 0 and 1 (6 x dwordx4, coalesced). ---
    const v4f* pA = pts4 + 3 * (j + 0 * T);
    v4f a0 = pA[0], a1 = pA[1], a2 = pA[2];
    const v4f* pB = pts4 + 3 * (j + 1 * T);
    v4f b0 = pB[0], b1 = pB[1], b2 = pB[2];

    // --- Iter 0: prefetch chunk 2, compute+gather chunk 0. ---
    const v4f* pC = pts4 + 3 * (j + 2 * T);
    v4f c0 = pC[0], c1 = pC[1], c2 = pC[2];

    int idxA[4]; bool valA[4];
    compute_idx4(slut, a0, a1, a2, idxA, valA);   // waits only on a* (partial vmcnt)
    float vA[4];
#pragma unroll
    for (int k = 0; k < 4; ++k) vA[k] = grid[idxA[k]];

    // --- Iter 1: prefetch chunk 3, compute+gather chunk 1. ---
    const v4f* pD = pts4 + 3 * (j + 3 * T);
    v4f d0 = pD[0], d1 = pD[1], d2 = pD[2];

    int idxB[4]; bool valB[4];
    compute_idx4(slut, b0, b1, b2, idxB, valB);
    float vB[4];
#pragma unroll
    for (int k = 0; k < 4; ++k) vB[k] = grid[idxB[k]];

    // --- Iter 2: compute+gather chunk 2. ---
    int idxC[4]; bool valC[4];
    compute_idx4(slut, c0, c1, c2, idxC, valC);
    float vC[4];
#pragma unroll
    for (int k = 0; k < 4; ++k) vC[k] = grid[idxC[k]];

    // --- Iter 3: compute+gather chunk 3. ---
    int idxD[4]; bool valD[4];
    compute_idx4(slut, d0, d1, d2, idxD, valD);
    float vD[4];
#pragma unroll
    for (int k = 0; k < 4; ++k) vD[k] = grid[idxD[k]];

    // --- Stores: descending vmcnt waits (12 / 8 / 4 / 0 gathers newer). ---
#pragma unroll
    for (int k = 0; k < 4; ++k) vA[k] = valA[k] ? vA[k] : 0.0f;
    v4f oA = {vA[0], vA[1], vA[2], vA[3]};
    out4[j + 0 * T] = oA;

#pragma unroll
    for (int k = 0; k < 4; ++k) vB[k] = valB[k] ? vB[k] : 0.0f;
    v4f oB = {vB[0], vB[1], vB[2], vB[3]};
    out4[j + 1 * T] = oB;

#pragma unroll
    for (int k = 0; k < 4; ++k) vC[k] = valC[k] ? vC[k] : 0.0f;
    v4f oC = {vC[0], vC[1], vC[2], vC[3]};
    out4[j + 2 * T] = oC;

#pragma unroll
    for (int k = 0; k < 4; ++k) vD[k] = valD[k] ? vD[k] : 0.0f;
    v4f oD = {vD[0], vD[1], vD[2], vD[3]};
    out4[j + 3 * T] = oD;
}

extern "C" void kernel_launch(void* const* d_in, const int* in_sizes, int n_in,
                              void* d_out, int out_size, void* d_ws, size_t ws_size,
                              hipStream_t stream) {
    const float* pts    = (const float*)d_in[0];
    const float* grid   = (const float*)d_in[1];
    const int*   lookup = (const int*)d_in[2];
    float*       out    = (float*)d_out;

    // out_size = 4194304 points; 16 points per thread (4 chunks of 4).
    int T = out_size / 16;                      // 262144 threads
    int threads = 128;
    int blocks = (T + threads - 1) / threads;   // 2048 blocks = 8/CU
    occ_forest_kernel<<<blocks, threads, 0, stream>>>(
        (const v4f*)pts, grid, lookup, (v4f*)out, T);
}